// Round 2
// baseline (5731.219 us; speedup 1.0000x reference)
//
#include <hip/hip_runtime.h>

typedef unsigned int u32;
typedef unsigned short u16;
typedef __attribute__((ext_vector_type(8))) short bf8v;   // 8 x bf16 (4 VGPRs)
typedef __attribute__((ext_vector_type(4))) float f32x4;  // MFMA C/D

#define NB 1024
#define NL 128
#define NH 256

// ---------------- workspace layout (byte offsets) ----------------
// packed weights: B-fragment tiles, tile(tn,kt) = 64 lanes x 8 bf16 = 1KB,
// element: W[tn*16 + (lane&15)][kt*32 + (lane>>4)*8 + i]
#define WS_WHH(g,l)  ((size_t)((g)*2+(l)) * 393216ull)              // 4 x (48*8 tiles)
#define WS_WIHX(g)   (1572864ull + (size_t)(g)*49152ull)            // l0 ih: 48*1 tiles (K=32: x0..2,1-col)
#define WS_WIH1(g)   (1671168ull + (size_t)(g)*442368ull)           // l1 ih: 48*9 tiles (K=288: bias col @256)
#define WS_WSPK      2555904ull                                      // W_s 16*8 tiles
#define WS_WEPK      2686976ull                                      // W_e 16*8 tiles
#define WS_AE        2818048ull                                      // bf16 attn_enc TRANSPOSED [b][h][s]
#define WS_HTOP      (WS_AE + 67108864ull)                           // bf16 [2][129][B][H]  (t=0 -> h0 top)
#define WS_HL0       (WS_HTOP + 135266304ull)                        // bf16 [2][128][B][H]  (post-step l0 h)
#define WS_P         (WS_HL0 + 134217728ull)                         // f32  [2][B][L] partial output dots

struct Ins { const float* p[23]; };

__device__ __forceinline__ u16 f2b(float f) {            // f32 -> bf16 RNE
  u32 u = __builtin_bit_cast(u32, f);
  u += 0x7fffu + ((u >> 16) & 1u);
  return (u16)(u >> 16);
}
__device__ __forceinline__ float b2f_lo(u32 w) { return __builtin_bit_cast(float, w << 16); }
__device__ __forceinline__ float b2f_hi(u32 w) { return __builtin_bit_cast(float, w & 0xffff0000u); }
__device__ __forceinline__ float upk(const uint4& q, int i) {
  u32 w = (i < 2) ? q.x : (i < 4) ? q.y : (i < 6) ? q.z : q.w;
  return (i & 1) ? b2f_hi(w) : b2f_lo(w);
}
__device__ __forceinline__ float frcp(float x) { return __builtin_amdgcn_rcpf(x); }
__device__ __forceinline__ float sigm(float x)  { return frcp(1.f + __expf(-x)); }
__device__ __forceinline__ float tanh_f(float x){ return 1.f - 2.f*frcp(1.f + __expf(2.f*x)); }

// mfma_f32_16x16x32_bf16 lane layouts (guide m89/m91-verified family):
//   A arg: lane holds A[lane&15][8*(lane>>4)+i]
//   B arg: lane holds B[8*(lane>>4)+i][lane&15]
//   C/D  : reg r  =  D[4*(lane>>4)+r][lane&15]
__device__ __forceinline__ f32x4 MF(bf8v a, bf8v b, f32x4 c) {
  return __builtin_amdgcn_mfma_f32_16x16x32_bf16(a, b, c, 0, 0, 0);
}
__device__ __forceinline__ bf8v ld8(const u16* p) {      // 16B fragment load (global or LDS)
  return __builtin_bit_cast(bf8v, *(const uint4*)p);
}

// ---------------- weight packing ----------------
__global__ void k_pack(Ins in, char* ws) {
  int tile = blockIdx.x*4 + (threadIdx.x >> 6);          // 2752 tiles total
  int lane = threadIdx.x & 63, llo = lane & 15, lhi = lane >> 4;
  float v[8];
  u16* dst;
  if (tile < 1536) {                                      // w_hh (4 matrices, 768x256)
    int mat = tile/384, rem = tile%384, tn = rem >> 3, kt = rem & 7;
    int g = mat >> 1, l = mat & 1;
    const float* w = in.p[4 + g*8 + l*4];
    int n = tn*16 + llo;
    #pragma unroll
    for (int i = 0; i < 8; i++) { int k = kt*32 + lhi*8 + i; v[i] = w[n*256 + k]; }
    dst = (u16*)(ws + WS_WHH(g,l)) + ((size_t)(tn*8+kt)*64 + lane)*8;
  } else if (tile < 1632) {                               // l0 w_ih padded (768x32, bias col @3)
    int t2 = tile-1536; int g = t2/48, tn = t2%48;
    const float* w  = in.p[3+g*8];
    const float* bi = in.p[5+g*8];
    const float* bh = in.p[6+g*8];
    int n = tn*16 + llo;
    #pragma unroll
    for (int i = 0; i < 8; i++) {
      int k = lhi*8 + i;
      v[i] = (k < 3) ? w[n*3+k] : (k == 3 ? (bi[n] + (n < 512 ? bh[n] : 0.f)) : 0.f);
    }
    dst = (u16*)(ws + WS_WIHX(g)) + ((size_t)tn*64 + lane)*8;
  } else if (tile < 2496) {                               // l1 w_ih padded (768x288, bias col @256)
    int t2 = tile-1632; int g = t2/432, rem = t2%432, tn = rem/9, kt = rem%9;
    const float* w  = in.p[7+g*8];
    const float* bi = in.p[9+g*8];
    const float* bh = in.p[10+g*8];
    int n = tn*16 + llo;
    #pragma unroll
    for (int i = 0; i < 8; i++) {
      int k = kt*32 + lhi*8 + i;
      v[i] = (k < 256) ? w[n*256+k] : (k == 256 ? (bi[n] + (n < 512 ? bh[n] : 0.f)) : 0.f);
    }
    dst = (u16*)(ws + WS_WIH1(g)) + ((size_t)(tn*9+kt)*64 + lane)*8;
  } else if (tile < 2624) {                               // W_s = attn_W[:, :256]
    int t2 = tile-2496, tn = t2 >> 3, kt = t2 & 7;
    const float* aw = in.p[19]; int n = tn*16 + llo;
    #pragma unroll
    for (int i = 0; i < 8; i++) { int k = kt*32 + lhi*8 + i; v[i] = aw[n*512 + k]; }
    dst = (u16*)(ws + WS_WSPK) + ((size_t)(tn*8+kt)*64 + lane)*8;
  } else {                                                // W_e = attn_W[:, 256:]
    int t2 = tile-2624, tn = t2 >> 3, kt = t2 & 7;
    const float* aw = in.p[19]; int n = tn*16 + llo;
    #pragma unroll
    for (int i = 0; i < 8; i++) { int k = kt*32 + lhi*8 + i; v[i] = aw[n*512 + 256 + k]; }
    dst = (u16*)(ws + WS_WEPK) + ((size_t)(tn*8+kt)*64 + lane)*8;
  }
  uint4 pk;
  pk.x = (u32)f2b(v[0]) | ((u32)f2b(v[1]) << 16);
  pk.y = (u32)f2b(v[2]) | ((u32)f2b(v[3]) << 16);
  pk.z = (u32)f2b(v[4]) | ((u32)f2b(v[5]) << 16);
  pk.w = (u32)f2b(v[6]) | ((u32)f2b(v[7]) << 16);
  *(uint4*)dst = pk;
}

// Hall_top[g][0] = h0[1]  (both GRUs share h0)
__global__ void k_hall0(Ins in, char* ws) {
  int idx = blockIdx.x*256 + threadIdx.x;                 // 0..524287
  int g = idx >> 18, r = idx & 262143;
  u16* ht = (u16*)(ws + WS_HTOP) + (size_t)g*(129ull*NB*NH);
  ht[r] = f2b(in.p[2][262144 + r]);
}

// attn_enc[b][h][s] = sum_e eh[b,s,e] * W_e[h,e]   (stored transposed for energy kernel)
__global__ __launch_bounds__(512, 2) void k_attn_enc(Ins in, char* ws) {
  __shared__ __align__(16) u16 alds[128*280];             // A tile [s][e], padded stride 280
  const float* eh = in.p[1];
  const u16* wep = (const u16*)(ws + WS_WEPK);
  u16* ae = (u16*)(ws + WS_AE);
  int b = blockIdx.x, tid = threadIdx.x;
  int w = tid >> 6, lane = tid & 63, llo = lane & 15, lhi = lane >> 4;
  for (int c = tid; c < 4096; c += 512) {                 // stage eh[b] as bf16
    int row = c >> 5, cc = c & 31;
    const float* s = eh + ((size_t)(b*128 + row))*256 + cc*8;
    float4 f0 = *(const float4*)s, f1 = *(const float4*)(s+4);
    uint4 pk;
    pk.x = (u32)f2b(f0.x) | ((u32)f2b(f0.y) << 16);
    pk.y = (u32)f2b(f0.z) | ((u32)f2b(f0.w) << 16);
    pk.z = (u32)f2b(f1.x) | ((u32)f2b(f1.y) << 16);
    pk.w = (u32)f2b(f1.z) | ((u32)f2b(f1.w) << 16);
    *(uint4*)(alds + row*280 + cc*8) = pk;
  }
  __syncthreads();
  bf8v bf[2][8];
  #pragma unroll
  for (int nt = 0; nt < 2; nt++)
    #pragma unroll
    for (int kt = 0; kt < 8; kt++)
      bf[nt][kt] = ld8(wep + (((size_t)(2*w+nt)*8 + kt)*64 + lane)*8);
  for (int mt = 0; mt < 8; mt++) {
    bf8v af[8];
    #pragma unroll
    for (int kt = 0; kt < 8; kt++)
      af[kt] = ld8(alds + (16*mt + llo)*280 + kt*32 + lhi*8);
    #pragma unroll
    for (int nt = 0; nt < 2; nt++) {
      f32x4 c = {0.f,0.f,0.f,0.f};
      #pragma unroll
      for (int kt = 0; kt < 8; kt++) c = MF(af[kt], bf[nt][kt], c);
      int h = (2*w+nt)*16 + llo;
      int s0 = 16*mt + 4*lhi;                             // C rows = s within this b
      uint2 q;
      q.x = (u32)f2b(c[0]) | ((u32)f2b(c[1]) << 16);
      q.y = (u32)f2b(c[2]) | ((u32)f2b(c[3]) << 16);
      *(uint2*)(ae + (size_t)b*32768 + h*128 + s0) = q;
    }
  }
}

// ---------------- recurrent pass: one layer, both GRUs (grid.y) ----------------
// BB=32 batches/WG, 8 waves; wave w owns gate cols [32w,32w+32) of r,z,n chunks.
// Accumulator (C/D) convention everywhere in the epilogue:
//   batch row (within 32) = 16*m + 4*lhi + r ; h column = 32*w + 16*p + llo
template<int LAYER>
__global__ __launch_bounds__(512, 2) void k_rec(Ins in, char* ws) {
  __shared__ __align__(16) u16 hlds[32*280];              // h (bf16) for A-fragments
  __shared__ __align__(16) u16 xpad[32*32];               // l0: x padded to K=32 (col3 = 1.0)
  const int g = blockIdx.y, b0 = blockIdx.x*32, tid = threadIdx.x;
  const int w = tid >> 6, lane = tid & 63, llo = lane & 15, lhi = lane >> 4;

  const u16* whh = (const u16*)(ws + WS_WHH(g, LAYER));
  const u16* wgi = (const u16*)(ws + (LAYER == 0 ? WS_WIHX(g) : WS_WIH1(g)));
  const float* bhh = in.p[LAYER == 0 ? (6 + g*8) : (10 + g*8)];
  const float* h0  = in.p[2] + (size_t)LAYER*(NB*NH);
  const float* recv = in.p[0];
  const u16* hl0 = (const u16*)(ws + WS_HL0) + (size_t)g*(128ull*NB*NH);
  u16* hout = (LAYER == 0)
    ? (u16*)(ws + WS_HL0)  + (size_t)g*(128ull*NB*NH)
    : (u16*)(ws + WS_HTOP) + (size_t)g*(129ull*NB*NH) + (size_t)(NB*NH);  // t+1 slots

  // n-gate b_hh, accumulator layout: col = 32w + 16p + llo (constant over r)
  float bhhn[2];
  #pragma unroll
  for (int p = 0; p < 2; p++) bhhn[p] = bhh[512 + 32*w + 16*p + llo];

  float hst[2][2][4];                                     // [m][p][r]
  #pragma unroll
  for (int m = 0; m < 2; m++)
    #pragma unroll
    for (int r = 0; r < 4; r++) {
      int row = 16*m + 4*lhi + r;
      #pragma unroll
      for (int p = 0; p < 2; p++) {
        int col = 32*w + 16*p + llo;
        float hv = h0[(size_t)(b0 + row)*NH + col];
        hst[m][p][r] = hv;
        hlds[row*280 + col] = f2b(hv);
      }
    }
  if (LAYER == 0) {
    ((u32*)xpad)[tid & 511] = 0u;                         // 512 dwords = whole xpad
    __syncthreads();
    if (tid < 32) {
      const float* x = recv + (size_t)(b0 + tid)*(NL*3);
      uint2 q;
      q.x = (u32)f2b(x[0]) | ((u32)f2b(x[1]) << 16);
      q.y = (u32)f2b(x[2]) | (0x3f80u << 16);             // col3 = 1.0 (bias)
      *(uint2*)(xpad + tid*32) = q;
    }
  }

  #pragma unroll 1
  for (int t = 0; t < NL; t++) {
    __syncthreads();                                      // h/x tiles ready
    f32x4 aR[2][2], aZ[2][2], aNi[2][2], aNh[2][2];
    #pragma unroll
    for (int m = 0; m < 2; m++)
      #pragma unroll
      for (int p = 0; p < 2; p++) {
        f32x4 z = {0.f,0.f,0.f,0.f};
        aR[m][p]=z; aZ[m][p]=z; aNi[m][p]=z; aNh[m][p]=z;
      }
    // ----- gi part -----
    if (LAYER == 0) {
      bf8v xf[2];
      #pragma unroll
      for (int m = 0; m < 2; m++) xf[m] = ld8(xpad + (16*m + llo)*32 + lhi*8);
      #pragma unroll
      for (int q = 0; q < 3; q++)
        #pragma unroll
        for (int p = 0; p < 2; p++) {
          bf8v bt = ld8(wgi + ((size_t)(16*q + 2*w + p)*64 + lane)*8);
          #pragma unroll
          for (int m = 0; m < 2; m++) {
            f32x4 a0 = (q==0) ? aR[m][p] : (q==1) ? aZ[m][p] : aNi[m][p];
            a0 = MF(xf[m], bt, a0);
            if (q==0) aR[m][p]=a0; else if (q==1) aZ[m][p]=a0; else aNi[m][p]=a0;
          }
        }
    } else {
      for (int kt = 0; kt < 9; kt++) {
        bf8v gf[2];
        if (kt < 8) {
          #pragma unroll
          for (int m = 0; m < 2; m++)
            gf[m] = ld8(hl0 + ((size_t)t*NB + b0 + 16*m + llo)*NH + kt*32 + lhi*8);
        } else {
          bf8v bb = {0,0,0,0,0,0,0,0};
          if (lhi == 0) bb[0] = (short)0x3f80;            // bias col: A[.][256] = 1.0
          gf[0] = bb; gf[1] = bb;
        }
        #pragma unroll
        for (int q = 0; q < 3; q++)
          #pragma unroll
          for (int p = 0; p < 2; p++) {
            bf8v bt = ld8(wgi + (((size_t)(16*q + 2*w + p)*9 + kt)*64 + lane)*8);
            #pragma unroll
            for (int m = 0; m < 2; m++) {
              f32x4 a0 = (q==0) ? aR[m][p] : (q==1) ? aZ[m][p] : aNi[m][p];
              a0 = MF(gf[m], bt, a0);
              if (q==0) aR[m][p]=a0; else if (q==1) aZ[m][p]=a0; else aNi[m][p]=a0;
            }
          }
      }
    }
    // ----- gh = h @ w_hh^T -----
    for (int kt = 0; kt < 8; kt++) {
      bf8v hf[2];
      #pragma unroll
      for (int m = 0; m < 2; m++)
        hf[m] = ld8(hlds + (16*m + llo)*280 + kt*32 + lhi*8);
      #pragma unroll
      for (int q = 0; q < 3; q++)
        #pragma unroll
        for (int p = 0; p < 2; p++) {
          bf8v bt = ld8(whh + (((size_t)(16*q + 2*w + p)*8 + kt)*64 + lane)*8);
          #pragma unroll
          for (int m = 0; m < 2; m++) {
            f32x4 a0 = (q==0) ? aR[m][p] : (q==1) ? aZ[m][p] : aNh[m][p];
            a0 = MF(hf[m], bt, a0);
            if (q==0) aR[m][p]=a0; else if (q==1) aZ[m][p]=a0; else aNh[m][p]=a0;
          }
        }
    }
    // ----- GRU cell epilogue (fp32, accumulator layout) -----
    u16 hv16[2][2][4];
    #pragma unroll
    for (int m = 0; m < 2; m++)
      #pragma unroll
      for (int p = 0; p < 2; p++)
        #pragma unroll
        for (int r = 0; r < 4; r++) {
          float rr = sigm(aR[m][p][r]);
          float zz = sigm(aZ[m][p][r]);
          float nn = tanh_f(aNi[m][p][r] + rr*(aNh[m][p][r] + bhhn[p]));
          float h  = nn + zz*(hst[m][p][r] - nn);
          hst[m][p][r] = h; hv16[m][p][r] = f2b(h);
        }
    __syncthreads();                                      // everyone done reading old h
    #pragma unroll
    for (int m = 0; m < 2; m++)
      #pragma unroll
      for (int r = 0; r < 4; r++) {
        int row = 16*m + 4*lhi + r;
        u16* lrow = hlds + row*280;
        u16* grow = hout + ((size_t)t*NB + b0 + row)*NH;
        #pragma unroll
        for (int p = 0; p < 2; p++) {
          int col = 32*w + 16*p + llo;
          lrow[col] = hv16[m][p][r];
          grow[col] = hv16[m][p][r];
        }
      }
    if (LAYER == 0 && t < NL-1 && tid < 32) {             // stage x for t+1
      const float* x = recv + (size_t)(b0 + tid)*(NL*3) + (size_t)(t+1)*3;
      uint2 q;
      q.x = (u32)f2b(x[0]) | ((u32)f2b(x[1]) << 16);
      q.y = (u32)f2b(x[2]) | (0x3f80u << 16);
      *(uint2*)(xpad + tid*32) = q;
    }
  }
}

// ---------------- fused attention + output partials: one WG per (GRU g, batch b) ----------------
// sp = Hprev @ W_s^T (MFMA, into LDS) ; energy = sum_h v*tanh(sp+ae) ; softmax over s ;
// ctx = sum_s a*eh ; p[g][b][t] = o.Wo + ctx.Wc   (per-lane tile: 4 t x 8 s)
__global__ __launch_bounds__(512, 2) void k_energy(Ins in, char* ws) {
  __shared__ __align__(16) char smem[142336];
  u16*   aeT  = (u16*)smem;                               // [256 h][136] bf16 (union: aF)
  float* aF   = (float*)smem;                             // [128 t][132] f32 softmax weights
  u16*   spm  = (u16*)(smem + 69632);                     // [128 t][264] bf16 (later: eh [s][264])
  float* wout = (float*)(smem + 137216);                  // out_W (1024)
  float* vv   = (float*)(smem + 141312);                  // v (256)
  const int g = blockIdx.y, b = blockIdx.x, tid = threadIdx.x;
  const int w = tid >> 6, lane = tid & 63, llo = lane & 15, lhi = lane >> 4;
  const u16* ae_g = (const u16*)(ws + WS_AE) + (size_t)b*32768;
  const u16* htop = (const u16*)(ws + WS_HTOP) + (size_t)g*(129ull*NB*NH);
  const u16* wsp  = (const u16*)(ws + WS_WSPK);
  float* pw = (float*)(ws + WS_P) + (size_t)g*(NB*NL) + (size_t)b*NL;

  for (int c = tid; c < 1024; c += 512) wout[c] = in.p[21][c];
  for (int c = tid; c < 256;  c += 512) vv[c]   = in.p[20][c];
  for (int c = tid; c < 4096; c += 512) {                 // stage ae[b] ([h][s], bf16)
    int h = c >> 4, sc = c & 15;
    *(uint4*)(aeT + h*136 + sc*8) = *(const uint4*)(ae_g + h*128 + sc*8);
  }
  __syncthreads();

  { // sp[t][h] = sum_k Hprev[t][k] * W_s[h][k]  (M = t, fixed b)
    bf8v bf[2][8];
    #pragma unroll
    for (int nt = 0; nt < 2; nt++)
      #pragma unroll
      for (int kt = 0; kt < 8; kt++)
        bf[nt][kt] = ld8(wsp + (((size_t)(2*w+nt)*8 + kt)*64 + lane)*8);
    for (int mt = 0; mt < 8; mt++) {
      bf8v af[8];
      #pragma unroll
      for (int kt = 0; kt < 8; kt++)
        af[kt] = ld8(htop + ((size_t)(16*mt + llo)*NB + b)*NH + kt*32 + lhi*8);
      #pragma unroll
      for (int nt = 0; nt < 2; nt++) {
        f32x4 c = {0.f,0.f,0.f,0.f};
        #pragma unroll
        for (int kt = 0; kt < 8; kt++) c = MF(af[kt], bf[nt][kt], c);
        int h = (2*w+nt)*16 + llo, t0 = 16*mt + 4*lhi;
        #pragma unroll
        for (int r = 0; r < 4; r++) spm[(t0+r)*264 + h] = f2b(c[r]);
      }
    }
  }
  __syncthreads();

  // ----- energy accumulation: lane tile = 4 t x 8 s, loop over all 256 h -----
  const int tt = 4*w + lhi;                               // t_tile 0..31 ; t = 4*tt+a
  const int sb = 8*llo;                                   // s base
  float acc[4][8];
  #pragma unroll
  for (int a = 0; a < 4; a++)
    #pragma unroll
    for (int s8 = 0; s8 < 8; s8++) acc[a][s8] = 0.f;
  for (int hc = 0; hc < 32; hc++) {
    uint4 sp8[4];
    #pragma unroll
    for (int a = 0; a < 4; a++) sp8[a] = *(const uint4*)(spm + (4*tt+a)*264 + hc*8);
    float4 v0 = *(const float4*)(vv + hc*8), v1 = *(const float4*)(vv + hc*8 + 4);
    float vl[8] = {v0.x,v0.y,v0.z,v0.w,v1.x,v1.y,v1.z,v1.w};
    #pragma unroll
    for (int i = 0; i < 8; i++) {
      uint4 ae8 = *(const uint4*)(aeT + (hc*8+i)*136 + sb);   // 8 s-values of ae at this h
      float sv[4];
      #pragma unroll
      for (int a = 0; a < 4; a++) sv[a] = upk(sp8[a], i);
      float vi = vl[i];
      #pragma unroll
      for (int s8 = 0; s8 < 8; s8++) {
        float av = upk(ae8, s8);
        #pragma unroll
        for (int a = 0; a < 4; a++) acc[a][s8] += vi * tanh_f(sv[a] + av);
      }
    }
  }
  __syncthreads();                                        // done reading aeT/spm

  // ----- softmax over s (16-lane groups share t) -----
  float aw[4][8];
  #pragma unroll
  for (int a = 0; a < 4; a++) {
    float mx = acc[a][0];
    #pragma unroll
    for (int s8 = 1; s8 < 8; s8++) mx = fmaxf(mx, acc[a][s8]);
    for (int d = 1; d < 16; d <<= 1) mx = fmaxf(mx, __shfl_xor(mx, d));
    float sum = 0.f;
    #pragma unroll
    for (int s8 = 0; s8 < 8; s8++) { float e = __expf(acc[a][s8] - mx); aw[a][s8] = e; sum += e; }
    for (int d = 1; d < 16; d <<= 1) sum += __shfl_xor(sum, d);
    float dn = frcp(sum);
    #pragma unroll
    for (int s8 = 0; s8 < 8; s8++) aw[a][s8] *= dn;
  }
  #pragma unroll
  for (int a = 0; a < 4; a++) {                           // a-weights -> LDS (over aeT region)
    float4 q0 = {aw[a][0],aw[a][1],aw[a][2],aw[a][3]};
    float4 q1 = {aw[a][4],aw[a][5],aw[a][6],aw[a][7]};
    *(float4*)(aF + (4*tt+a)*132 + sb)     = q0;
    *(float4*)(aF + (4*tt+a)*132 + sb + 4) = q1;
  }
  for (int c = tid; c < 4096; c += 512) {                 // stage eh[b] bf16 (over spm region)
    int s = c >> 5, ec = c & 31;
    const float* src = in.p[1] + ((size_t)(b*128 + s))*256 + ec*8;
    float4 f0 = *(const float4*)src, f1 = *(const float4*)(src+4);
    uint4 pk;
    pk.x = (u32)f2b(f0.x) | ((u32)f2b(f0.y) << 16);
    pk.y = (u32)f2b(f0.z) | ((u32)f2b(f0.w) << 16);
    pk.z = (u32)f2b(f1.x) | ((u32)f2b(f1.y) << 16);
    pk.w = (u32)f2b(f1.z) | ((u32)f2b(f1.w) << 16);
    *(uint4*)(spm + s*264 + ec*8) = pk;
  }
  __syncthreads();

  // ----- ctx[t][e] = sum_s a[t,s]*eh[s,e] ; lane owns e = 8*llo..+8 and +128 -----
  float cacc[4][16];
  #pragma unroll
  for (int a = 0; a < 4; a++)
    #pragma unroll
    for (int i = 0; i < 16; i++) cacc[a][i] = 0.f;
  for (int s = 0; s < 128; s++) {
    float av[4];
    #pragma unroll
    for (int a = 0; a < 4; a++) av[a] = aF[(4*tt+a)*132 + s];
    uint4 e0 = *(const uint4*)(spm + s*264 + 8*llo);
    uint4 e1 = *(const uint4*)(spm + s*264 + 128 + 8*llo);
    #pragma unroll
    for (int i = 0; i < 8; i++) {
      float f0 = upk(e0, i), f1 = upk(e1, i);
      #pragma unroll
      for (int a = 0; a < 4; a++) { cacc[a][i] += av[a]*f0; cacc[a][8+i] += av[a]*f1; }
    }
  }
  // ----- partial output dot: p = o.Wo + ctx.Wc -----
  const int cb = 256 + g*512, ob = g*512;
  #pragma unroll
  for (int a = 0; a < 4; a++) {
    int t = 4*tt + a;
    float pv = 0.f;
    #pragma unroll
    for (int i = 0; i < 8; i++) {
      pv += cacc[a][i]   * wout[cb + 8*llo + i];
      pv += cacc[a][8+i] * wout[cb + 128 + 8*llo + i];
    }
    uint4 o0 = *(const uint4*)(htop + ((size_t)(t+1)*NB + b)*NH + 8*llo);
    uint4 o1 = *(const uint4*)(htop + ((size_t)(t+1)*NB + b)*NH + 128 + 8*llo);
    #pragma unroll
    for (int i = 0; i < 8; i++) {
      pv += upk(o0, i) * wout[ob + 8*llo + i];
      pv += upk(o1, i) * wout[ob + 128 + 8*llo + i];
    }
    for (int d = 1; d < 16; d <<= 1) pv += __shfl_xor(pv, d);
    if (llo == 0) pw[t] = pv;
  }
}

// out[b,t] = sigmoid(p1[b,t] + p2[b, idx(t)] + out_b)
__global__ void k_final(Ins in, char* ws, float* out) {
  int idx = blockIdx.x*256 + threadIdx.x;                 // 131072
  int b = idx >> 7, t = idx & 127;
  const float* pw = (const float*)(ws + WS_P);
  float p1 = pw[(size_t)b*NL + t];
  int t2 = (t >= 117) ? 127 : (t + 10);
  float p2 = pw[(size_t)NB*NL + (size_t)b*NL + t2];
  out[idx] = sigm(p1 + p2 + in.p[22][0]);
}

extern "C" void kernel_launch(void* const* d_in, const int* in_sizes, int n_in,
                              void* d_out, int out_size, void* d_ws, size_t ws_size,
                              hipStream_t stream) {
  Ins in;
  for (int i = 0; i < 23; i++) in.p[i] = (const float*)d_in[i];
  char* ws = (char*)d_ws;
  k_pack    <<<688, 256, 0, stream>>>(in, ws);
  k_hall0   <<<2048, 256, 0, stream>>>(in, ws);
  k_attn_enc<<<1024, 512, 0, stream>>>(in, ws);
  k_rec<0>  <<<dim3(32, 2), 512, 0, stream>>>(in, ws);
  k_rec<1>  <<<dim3(32, 2), 512, 0, stream>>>(in, ws);
  k_energy  <<<dim3(1024, 2), 512, 0, stream>>>(in, ws);
  k_final   <<<512, 256, 0, stream>>>(in, ws, (float*)d_out);
}

// Round 3
// 2712.536 us; speedup vs baseline: 2.1129x; 2.1129x over previous
//
#include <hip/hip_runtime.h>

typedef unsigned int u32;
typedef unsigned short u16;
typedef __attribute__((ext_vector_type(8))) short bf8v;   // 8 x bf16 (4 VGPRs)
typedef __attribute__((ext_vector_type(4))) float f32x4;  // MFMA C/D

#define NB 1024
#define NL 128
#define NH 256

// ---------------- workspace layout (byte offsets) ----------------
#define WS_WHH(g,l)  ((size_t)((g)*2+(l)) * 393216ull)              // 4 x (48*8 tiles)
#define WS_WIHX(g)   (1572864ull + (size_t)(g)*49152ull)            // l0 ih: 48*1 tiles (K=32)
#define WS_WIH1(g)   (1671168ull + (size_t)(g)*442368ull)           // l1 ih: 48*9 tiles (K=288, bias col @256)
#define WS_WSPK      2555904ull                                      // W_s 16*8 tiles
#define WS_WEPK      2686976ull                                      // W_e 16*8 tiles
#define WS_AE        2818048ull                                      // f16 E_ae = exp(2*attn_enc) [b][h][s]
#define WS_HTOP      (WS_AE + 67108864ull)                           // bf16 [2][129][B][H]
#define WS_HL0       (WS_HTOP + 135266304ull)                        // bf16 [2][128][B][H]
#define WS_P         (WS_HL0 + 134217728ull)                         // f32  [2][B][L]
#define WS_GI        340459520ull                                    // bf16 gi1 [t][b][768] (per g)
#define GI_SZ        201326592ull

struct Ins { const float* p[23]; };

__device__ __forceinline__ u16 f2b(float f) {            // f32 -> bf16 RNE
  u32 u = __builtin_bit_cast(u32, f);
  u += 0x7fffu + ((u >> 16) & 1u);
  return (u16)(u >> 16);
}
__device__ __forceinline__ float b2f(u16 h) { return __builtin_bit_cast(float, ((u32)h) << 16); }
__device__ __forceinline__ u16 f2h(float f) { _Float16 h = (_Float16)f; return __builtin_bit_cast(u16, h); }
__device__ __forceinline__ float h2f(u16 h) { return (float)__builtin_bit_cast(_Float16, h); }
__device__ __forceinline__ float upk(const uint4& q, int i) {   // bf16 unpack
  u32 w = (i < 2) ? q.x : (i < 4) ? q.y : (i < 6) ? q.z : q.w;
  return (i & 1) ? __builtin_bit_cast(float, w & 0xffff0000u)
                 : __builtin_bit_cast(float, w << 16);
}
__device__ __forceinline__ float upkh(const uint4& q, int i) {  // f16 unpack
  u32 w = (i < 2) ? q.x : (i < 4) ? q.y : (i < 6) ? q.z : q.w;
  return h2f((i & 1) ? (u16)(w >> 16) : (u16)(w & 0xffffu));
}
__device__ __forceinline__ float frcp(float x) { return __builtin_amdgcn_rcpf(x); }
__device__ __forceinline__ float sigm(float x)  { return frcp(1.f + __expf(-x)); }
__device__ __forceinline__ float tanh_f(float x){ return 1.f - 2.f*frcp(1.f + __expf(2.f*x)); }

__device__ __forceinline__ f32x4 MF(bf8v a, bf8v b, f32x4 c) {
  return __builtin_amdgcn_mfma_f32_16x16x32_bf16(a, b, c, 0, 0, 0);
}
__device__ __forceinline__ bf8v ld8(const u16* p) {
  return __builtin_bit_cast(bf8v, *(const uint4*)p);
}

// ---------------- weight packing (unchanged from R2) ----------------
__global__ void k_pack(Ins in, char* ws) {
  int tile = blockIdx.x*4 + (threadIdx.x >> 6);
  int lane = threadIdx.x & 63, llo = lane & 15, lhi = lane >> 4;
  float v[8];
  u16* dst;
  if (tile < 1536) {
    int mat = tile/384, rem = tile%384, tn = rem >> 3, kt = rem & 7;
    int g = mat >> 1, l = mat & 1;
    const float* w = in.p[4 + g*8 + l*4];
    int n = tn*16 + llo;
    #pragma unroll
    for (int i = 0; i < 8; i++) { int k = kt*32 + lhi*8 + i; v[i] = w[n*256 + k]; }
    dst = (u16*)(ws + WS_WHH(g,l)) + ((size_t)(tn*8+kt)*64 + lane)*8;
  } else if (tile < 1632) {
    int t2 = tile-1536; int g = t2/48, tn = t2%48;
    const float* w  = in.p[3+g*8];
    const float* bi = in.p[5+g*8];
    const float* bh = in.p[6+g*8];
    int n = tn*16 + llo;
    #pragma unroll
    for (int i = 0; i < 8; i++) {
      int k = lhi*8 + i;
      v[i] = (k < 3) ? w[n*3+k] : (k == 3 ? (bi[n] + (n < 512 ? bh[n] : 0.f)) : 0.f);
    }
    dst = (u16*)(ws + WS_WIHX(g)) + ((size_t)tn*64 + lane)*8;
  } else if (tile < 2496) {
    int t2 = tile-1632; int g = t2/432, rem = t2%432, tn = rem/9, kt = rem%9;
    const float* w  = in.p[7+g*8];
    const float* bi = in.p[9+g*8];
    const float* bh = in.p[10+g*8];
    int n = tn*16 + llo;
    #pragma unroll
    for (int i = 0; i < 8; i++) {
      int k = kt*32 + lhi*8 + i;
      v[i] = (k < 256) ? w[n*256+k] : (k == 256 ? (bi[n] + (n < 512 ? bh[n] : 0.f)) : 0.f);
    }
    dst = (u16*)(ws + WS_WIH1(g)) + ((size_t)(tn*9+kt)*64 + lane)*8;
  } else if (tile < 2624) {
    int t2 = tile-2496, tn = t2 >> 3, kt = t2 & 7;
    const float* aw = in.p[19]; int n = tn*16 + llo;
    #pragma unroll
    for (int i = 0; i < 8; i++) { int k = kt*32 + lhi*8 + i; v[i] = aw[n*512 + k]; }
    dst = (u16*)(ws + WS_WSPK) + ((size_t)(tn*8+kt)*64 + lane)*8;
  } else {
    int t2 = tile-2624, tn = t2 >> 3, kt = t2 & 7;
    const float* aw = in.p[19]; int n = tn*16 + llo;
    #pragma unroll
    for (int i = 0; i < 8; i++) { int k = kt*32 + lhi*8 + i; v[i] = aw[n*512 + 256 + k]; }
    dst = (u16*)(ws + WS_WEPK) + ((size_t)(tn*8+kt)*64 + lane)*8;
  }
  uint4 pk;
  pk.x = (u32)f2b(v[0]) | ((u32)f2b(v[1]) << 16);
  pk.y = (u32)f2b(v[2]) | ((u32)f2b(v[3]) << 16);
  pk.z = (u32)f2b(v[4]) | ((u32)f2b(v[5]) << 16);
  pk.w = (u32)f2b(v[6]) | ((u32)f2b(v[7]) << 16);
  *(uint4*)dst = pk;
}

__global__ void k_hall0(Ins in, char* ws) {
  int idx = blockIdx.x*256 + threadIdx.x;
  int g = idx >> 18, r = idx & 262143;
  u16* ht = (u16*)(ws + WS_HTOP) + (size_t)g*(129ull*NB*NH);
  ht[r] = f2b(in.p[2][262144 + r]);
}

// E_ae[b][h][s] = exp(2 * sum_e eh[b,s,e]*W_e[h,e]), fp16
__global__ __launch_bounds__(512, 2) void k_attn_enc(Ins in, char* ws) {
  __shared__ __align__(16) u16 alds[128*280];
  const float* eh = in.p[1];
  const u16* wep = (const u16*)(ws + WS_WEPK);
  u16* ae = (u16*)(ws + WS_AE);
  int b = blockIdx.x, tid = threadIdx.x;
  int w = tid >> 6, lane = tid & 63, llo = lane & 15, lhi = lane >> 4;
  for (int c = tid; c < 4096; c += 512) {
    int row = c >> 5, cc = c & 31;
    const float* s = eh + ((size_t)(b*128 + row))*256 + cc*8;
    float4 f0 = *(const float4*)s, f1 = *(const float4*)(s+4);
    uint4 pk;
    pk.x = (u32)f2b(f0.x) | ((u32)f2b(f0.y) << 16);
    pk.y = (u32)f2b(f0.z) | ((u32)f2b(f0.w) << 16);
    pk.z = (u32)f2b(f1.x) | ((u32)f2b(f1.y) << 16);
    pk.w = (u32)f2b(f1.z) | ((u32)f2b(f1.w) << 16);
    *(uint4*)(alds + row*280 + cc*8) = pk;
  }
  __syncthreads();
  bf8v bf[2][8];
  #pragma unroll
  for (int nt = 0; nt < 2; nt++)
    #pragma unroll
    for (int kt = 0; kt < 8; kt++)
      bf[nt][kt] = ld8(wep + (((size_t)(2*w+nt)*8 + kt)*64 + lane)*8);
  for (int mt = 0; mt < 8; mt++) {
    bf8v af[8];
    #pragma unroll
    for (int kt = 0; kt < 8; kt++)
      af[kt] = ld8(alds + (16*mt + llo)*280 + kt*32 + lhi*8);
    #pragma unroll
    for (int nt = 0; nt < 2; nt++) {
      f32x4 c = {0.f,0.f,0.f,0.f};
      #pragma unroll
      for (int kt = 0; kt < 8; kt++) c = MF(af[kt], bf[nt][kt], c);
      int h = (2*w+nt)*16 + llo;
      int s0 = 16*mt + 4*lhi;
      uint2 q;
      q.x = (u32)f2h(__expf(2.f*c[0])) | ((u32)f2h(__expf(2.f*c[1])) << 16);
      q.y = (u32)f2h(__expf(2.f*c[2])) | ((u32)f2h(__expf(2.f*c[3])) << 16);
      *(uint2*)(ae + (size_t)b*32768 + h*128 + s0) = q;
    }
  }
}

// ---------------- recurrent layer 0, both GRUs; BB=16, whh r,n cached in VGPRs ----------------
__global__ __launch_bounds__(512, 2) void k_rec0(Ins in, char* ws) {
  __shared__ __align__(16) u16 hlds[16*280];
  __shared__ __align__(16) u16 xpad[16*32];
  const int g = blockIdx.y, b0 = blockIdx.x*16, tid = threadIdx.x;
  const int w = tid >> 6, lane = tid & 63, llo = lane & 15, lhi = lane >> 4;

  const u16* whh = (const u16*)(ws + WS_WHH(g,0));
  const u16* wgi = (const u16*)(ws + WS_WIHX(g));
  const float* bhh = in.p[6 + g*8];
  const float* h0  = in.p[2];
  const float* recv = in.p[0];
  u16* hout = (u16*)(ws + WS_HL0) + (size_t)g*(128ull*NB*NH);

  float bhhn[2];
  #pragma unroll
  for (int p = 0; p < 2; p++) bhhn[p] = bhh[512 + 32*w + 16*p + llo];

  bf8v whhR[2][8], whhN[2][8];
  #pragma unroll
  for (int p = 0; p < 2; p++)
    #pragma unroll
    for (int kt = 0; kt < 8; kt++) {
      whhR[p][kt] = ld8(whh + (((size_t)(      2*w + p)*8 + kt)*64 + lane)*8);
      whhN[p][kt] = ld8(whh + (((size_t)(32 + 2*w + p)*8 + kt)*64 + lane)*8);
    }

  float hst[2][4];
  #pragma unroll
  for (int r = 0; r < 4; r++) {
    int row = 4*lhi + r;
    #pragma unroll
    for (int p = 0; p < 2; p++) {
      int col = 32*w + 16*p + llo;
      float hv = h0[(size_t)(b0 + row)*NH + col];
      hst[p][r] = hv;
      hlds[row*280 + col] = f2b(hv);
    }
  }
  if (tid < 256) ((u32*)xpad)[tid] = 0u;
  __syncthreads();
  if (tid < 16) {
    const float* x = recv + (size_t)(b0 + tid)*(NL*3);
    uint2 q;
    q.x = (u32)f2b(x[0]) | ((u32)f2b(x[1]) << 16);
    q.y = (u32)f2b(x[2]) | (0x3f80u << 16);
    *(uint2*)(xpad + tid*32) = q;
  }

  #pragma unroll 1
  for (int t = 0; t < NL; t++) {
    __syncthreads();
    bf8v xf = ld8(xpad + llo*32 + lhi*8);
    f32x4 aR[2], aZ[2], aNi[2], aNh[2];
    #pragma unroll
    for (int p = 0; p < 2; p++) {
      f32x4 z = {0.f,0.f,0.f,0.f};
      aR[p]=z; aZ[p]=z; aNi[p]=z; aNh[p]=z;
    }
    #pragma unroll
    for (int q = 0; q < 3; q++)
      #pragma unroll
      for (int p = 0; p < 2; p++) {
        bf8v bt = ld8(wgi + ((size_t)(16*q + 2*w + p)*64 + lane)*8);
        f32x4 a0 = (q==0) ? aR[p] : (q==1) ? aZ[p] : aNi[p];
        a0 = MF(xf, bt, a0);
        if (q==0) aR[p]=a0; else if (q==1) aZ[p]=a0; else aNi[p]=a0;
      }
    #pragma unroll
    for (int kt = 0; kt < 8; kt++) {
      bf8v hf = ld8(hlds + llo*280 + kt*32 + lhi*8);
      #pragma unroll
      for (int p = 0; p < 2; p++) {
        aR[p]  = MF(hf, whhR[p][kt], aR[p]);
        bf8v bz = ld8(whh + (((size_t)(16 + 2*w + p)*8 + kt)*64 + lane)*8);
        aZ[p]  = MF(hf, bz, aZ[p]);
        aNh[p] = MF(hf, whhN[p][kt], aNh[p]);
      }
    }
    u16 hv16[2][4];
    #pragma unroll
    for (int p = 0; p < 2; p++)
      #pragma unroll
      for (int r = 0; r < 4; r++) {
        float rr = sigm(aR[p][r]);
        float zz = sigm(aZ[p][r]);
        float nn = tanh_f(aNi[p][r] + rr*(aNh[p][r] + bhhn[p]));
        float h  = nn + zz*(hst[p][r] - nn);
        hst[p][r] = h; hv16[p][r] = f2b(h);
      }
    __syncthreads();
    #pragma unroll
    for (int r = 0; r < 4; r++) {
      int row = 4*lhi + r;
      #pragma unroll
      for (int p = 0; p < 2; p++) {
        int col = 32*w + 16*p + llo;
        hlds[row*280 + col] = hv16[p][r];
        hout[((size_t)t*NB + b0 + row)*NH + col] = hv16[p][r];
      }
    }
    if (t < NL-1 && tid < 16) {
      const float* x = recv + (size_t)(b0 + tid)*(NL*3) + (size_t)(t+1)*3;
      uint2 q;
      q.x = (u32)f2b(x[0]) | ((u32)f2b(x[1]) << 16);
      q.y = (u32)f2b(x[2]) | (0x3f80u << 16);
      *(uint2*)(xpad + tid*32) = q;
    }
  }
}

// gi1[t][b][768] (bf16) = hl0[g][t][b] @ wih1^T + biases (bias col trick)
__global__ __launch_bounds__(512, 4) void k_gi1(Ins in, char* ws, int g, unsigned long long gi_off) {
  __shared__ __align__(16) u16 alds[128*296];
  const int t = blockIdx.x >> 3, bt = blockIdx.x & 7, b0 = bt*128;
  const int tid = threadIdx.x;
  const int w = tid >> 6, lane = tid & 63, llo = lane & 15, lhi = lane >> 4;
  const u16* hl0 = (const u16*)(ws + WS_HL0) + (size_t)g*(128ull*NB*NH) + ((size_t)t*NB + b0)*NH;
  const u16* wgi = (const u16*)(ws + WS_WIH1(g));
  u16* gi = (u16*)(ws + gi_off) + ((size_t)t*NB + b0)*768;
  for (int c = tid; c < 4096; c += 512) {
    int row = c >> 5, ch = c & 31;
    *(uint4*)(alds + row*296 + ch*8) = *(const uint4*)(hl0 + row*NH + ch*8);
  }
  for (int c = tid; c < 640; c += 512) {
    int row = c/5, ch = c%5;
    uint4 v = {0u,0u,0u,0u};
    if (ch == 0) v.x = 0x3f80u;          // bf16 1.0 at k=256
    *(uint4*)(alds + row*296 + 256 + ch*8) = v;
  }
  __syncthreads();
  for (int mb = 0; mb < 8; mb++) {
    bf8v a[9];
    #pragma unroll
    for (int kt = 0; kt < 9; kt++)
      a[kt] = ld8(alds + (16*mb + llo)*296 + kt*32 + lhi*8);
    #pragma unroll 1
    for (int n = 0; n < 6; n++) {
      int tn = 6*w + n;
      f32x4 acc = {0.f,0.f,0.f,0.f};
      #pragma unroll
      for (int kt = 0; kt < 9; kt++) {
        bf8v bt8 = ld8(wgi + (((size_t)tn*9 + kt)*64 + lane)*8);
        acc = MF(a[kt], bt8, acc);
      }
      int col = tn*16 + llo, r0 = 16*mb + 4*lhi;
      #pragma unroll
      for (int r = 0; r < 4; r++)
        gi[(size_t)(r0 + r)*768 + col] = f2b(acc[r]);
    }
  }
}

// ---------------- recurrent layer 1; gh-only when GIPRE (gi precomputed) ----------------
template<int GIPRE>
__global__ __launch_bounds__(512, 2) void k_rec1(Ins in, char* ws, int gbase,
                                                 unsigned long long gi_off, unsigned long long gi_stride) {
  __shared__ __align__(16) u16 hlds[16*280];
  const int g = gbase + blockIdx.y, b0 = blockIdx.x*16, tid = threadIdx.x;
  const int w = tid >> 6, lane = tid & 63, llo = lane & 15, lhi = lane >> 4;

  const u16* whh = (const u16*)(ws + WS_WHH(g,1));
  const u16* wgi = (const u16*)(ws + WS_WIH1(g));
  const float* bhh = in.p[10 + g*8];
  const float* h0  = in.p[2] + (size_t)(NB*NH);
  const u16* hl0 = (const u16*)(ws + WS_HL0) + (size_t)g*(128ull*NB*NH);
  const u16* gi = (const u16*)(ws + gi_off + (size_t)blockIdx.y*gi_stride);
  u16* hout = (u16*)(ws + WS_HTOP) + (size_t)g*(129ull*NB*NH) + (size_t)(NB*NH);

  float bhhn[2];
  #pragma unroll
  for (int p = 0; p < 2; p++) bhhn[p] = bhh[512 + 32*w + 16*p + llo];

  bf8v whhR[2][8], whhN[2][8];
  #pragma unroll
  for (int p = 0; p < 2; p++)
    #pragma unroll
    for (int kt = 0; kt < 8; kt++) {
      whhR[p][kt] = ld8(whh + (((size_t)(      2*w + p)*8 + kt)*64 + lane)*8);
      whhN[p][kt] = ld8(whh + (((size_t)(32 + 2*w + p)*8 + kt)*64 + lane)*8);
    }

  float hst[2][4];
  #pragma unroll
  for (int r = 0; r < 4; r++) {
    int row = 4*lhi + r;
    #pragma unroll
    for (int p = 0; p < 2; p++) {
      int col = 32*w + 16*p + llo;
      float hv = h0[(size_t)(b0 + row)*NH + col];
      hst[p][r] = hv;
      hlds[row*280 + col] = f2b(hv);
    }
  }

  #pragma unroll 1
  for (int t = 0; t < NL; t++) {
    __syncthreads();
    f32x4 aR[2], aZ[2], aNi[2], aNh[2];
    float giN[2][4];
    if (GIPRE) {
      #pragma unroll
      for (int p = 0; p < 2; p++) {
        int col = 32*w + 16*p + llo;
        #pragma unroll
        for (int r = 0; r < 4; r++) {
          const u16* gr = gi + ((size_t)t*NB + b0 + 4*lhi + r)*768;
          aR[p][r]  = b2f(gr[      col]);
          aZ[p][r]  = b2f(gr[256 + col]);
          giN[p][r] = b2f(gr[512 + col]);
        }
        f32x4 z = {0.f,0.f,0.f,0.f};
        aNh[p] = z; aNi[p] = z;
      }
    } else {
      #pragma unroll
      for (int p = 0; p < 2; p++) {
        f32x4 z = {0.f,0.f,0.f,0.f};
        aR[p]=z; aZ[p]=z; aNi[p]=z; aNh[p]=z;
      }
      #pragma unroll 1
      for (int kt = 0; kt < 9; kt++) {
        bf8v gf;
        if (kt < 8) {
          gf = ld8(hl0 + ((size_t)t*NB + b0 + llo)*NH + kt*32 + lhi*8);
        } else {
          bf8v bb = {0,0,0,0,0,0,0,0};
          if (lhi == 0) bb[0] = (short)0x3f80;
          gf = bb;
        }
        #pragma unroll
        for (int q = 0; q < 3; q++)
          #pragma unroll
          for (int p = 0; p < 2; p++) {
            bf8v bt = ld8(wgi + (((size_t)(16*q + 2*w + p)*9 + kt)*64 + lane)*8);
            f32x4 a0 = (q==0) ? aR[p] : (q==1) ? aZ[p] : aNi[p];
            a0 = MF(gf, bt, a0);
            if (q==0) aR[p]=a0; else if (q==1) aZ[p]=a0; else aNi[p]=a0;
          }
      }
    }
    #pragma unroll
    for (int kt = 0; kt < 8; kt++) {
      bf8v hf = ld8(hlds + llo*280 + kt*32 + lhi*8);
      #pragma unroll
      for (int p = 0; p < 2; p++) {
        aR[p]  = MF(hf, whhR[p][kt], aR[p]);
        bf8v bz = ld8(whh + (((size_t)(16 + 2*w + p)*8 + kt)*64 + lane)*8);
        aZ[p]  = MF(hf, bz, aZ[p]);
        aNh[p] = MF(hf, whhN[p][kt], aNh[p]);
      }
    }
    u16 hv16[2][4];
    #pragma unroll
    for (int p = 0; p < 2; p++)
      #pragma unroll
      for (int r = 0; r < 4; r++) {
        float gin = GIPRE ? giN[p][r] : aNi[p][r];
        float rr = sigm(aR[p][r]);
        float zz = sigm(aZ[p][r]);
        float nn = tanh_f(gin + rr*(aNh[p][r] + bhhn[p]));
        float h  = nn + zz*(hst[p][r] - nn);
        hst[p][r] = h; hv16[p][r] = f2b(h);
      }
    __syncthreads();
    #pragma unroll
    for (int r = 0; r < 4; r++) {
      int row = 4*lhi + r;
      #pragma unroll
      for (int p = 0; p < 2; p++) {
        int col = 32*w + 16*p + llo;
        hlds[row*280 + col] = hv16[p][r];
        hout[((size_t)t*NB + b0 + row)*NH + col] = hv16[p][r];
      }
    }
  }
}

// ---------------- fused attention via exp/rcp identity + output partials ----------------
// tanh(sp+ae) = 1 - 2/(1+E_sp*E_ae); energy = Vtot - 2*sum_h v_h/(1+P_h)
__global__ __launch_bounds__(512, 2) void k_energy(Ins in, char* ws) {
  __shared__ __align__(16) char smem[141312];
  u16*   aeE  = (u16*)smem;                     // [256 h][136] f16  (later: eh f16 [128 s][264])
  float* spE  = (float*)(smem + 69632);         // [64 t][260] f32   (later: aF f32 [128 t][130])
  float* wout = (float*)(smem + 136192);        // 1024 f32
  float* vE   = (float*)(smem + 140288);        // 256 f32
  const int g = blockIdx.y, b = blockIdx.x, tid = threadIdx.x;
  const int w = tid >> 6, lane = tid & 63, llo = lane & 15, lhi = lane >> 4;
  const int gid = w*4 + lhi;
  const u16* ae_g = (const u16*)(ws + WS_AE) + (size_t)b*32768;
  const u16* htop = (const u16*)(ws + WS_HTOP) + (size_t)g*(129ull*NB*NH);
  const u16* wsp  = (const u16*)(ws + WS_WSPK);
  float* pw = (float*)(ws + WS_P) + (size_t)g*(NB*NL) + (size_t)b*NL;

  for (int c = tid; c < 1024; c += 512) wout[c] = in.p[21][c];
  for (int c = tid; c < 256;  c += 512) vE[c]   = in.p[20][c];
  for (int c = tid; c < 4096; c += 512) {
    int h = c >> 4, sc = c & 15;
    *(uint4*)(aeE + h*136 + sc*8) = *(const uint4*)(ae_g + h*128 + sc*8);
  }
  __syncthreads();
  float Vtot = 0.f;
  for (int i = 0; i < 64; i++) {
    float4 v4 = *(const float4*)(vE + i*4);
    Vtot += v4.x + v4.y + v4.z + v4.w;
  }

  float aw[2][2][8];
  #pragma unroll 1
  for (int half = 0; half < 2; half++) {
    __syncthreads();                            // spE readers of prev half done
    { // sp GEMM + exp(2*sp) -> spE for t in [64*half, 64*half+64)
      bf8v bf[2][8];
      #pragma unroll
      for (int nt = 0; nt < 2; nt++)
        #pragma unroll
        for (int kt = 0; kt < 8; kt++)
          bf[nt][kt] = ld8(wsp + (((size_t)(2*w+nt)*8 + kt)*64 + lane)*8);
      for (int mt = 0; mt < 4; mt++) {
        bf8v af[8];
        #pragma unroll
        for (int kt = 0; kt < 8; kt++)
          af[kt] = ld8(htop + ((size_t)(half*64 + 16*mt + llo)*NB + b)*NH + kt*32 + lhi*8);
        #pragma unroll
        for (int nt = 0; nt < 2; nt++) {
          f32x4 c = {0.f,0.f,0.f,0.f};
          #pragma unroll
          for (int kt = 0; kt < 8; kt++) c = MF(af[kt], bf[nt][kt], c);
          int hcol = (2*w+nt)*16 + llo, tl0 = 16*mt + 4*lhi;
          #pragma unroll
          for (int r = 0; r < 4; r++)
            spE[(tl0+r)*260 + hcol] = __expf(2.f*c[r]);
        }
      }
    }
    __syncthreads();
    // energy accumulation: tile = 2 t x 8 s; 4-h common-denominator combine
    float accS[2][8];
    #pragma unroll
    for (int i = 0; i < 2; i++)
      #pragma unroll
      for (int s = 0; s < 8; s++) accS[i][s] = 0.f;
    const int tl = gid*2;
    #pragma unroll 1
    for (int hq = 0; hq < 64; hq++) {
      int h0 = hq*4;
      float4 es0 = *(const float4*)(spE + tl*260 + h0);
      float4 es1 = *(const float4*)(spE + (tl+1)*260 + h0);
      float4 vq  = *(const float4*)(vE + h0);
      uint4 eaq0 = *(const uint4*)(aeE + (h0+0)*136 + llo*8);
      uint4 eaq1 = *(const uint4*)(aeE + (h0+1)*136 + llo*8);
      uint4 eaq2 = *(const uint4*)(aeE + (h0+2)*136 + llo*8);
      uint4 eaq3 = *(const uint4*)(aeE + (h0+3)*136 + llo*8);
      #pragma unroll
      for (int s = 0; s < 8; s++) {
        float ea0 = upkh(eaq0, s), ea1 = upkh(eaq1, s), ea2 = upkh(eaq2, s), ea3 = upkh(eaq3, s);
        {
          float D0 = fmaf(es0.x, ea0, 1.f), D1 = fmaf(es0.y, ea1, 1.f);
          float D2 = fmaf(es0.z, ea2, 1.f), D3 = fmaf(es0.w, ea3, 1.f);
          float na = fmaf(vq.y, D0, vq.x*D1), da = D0*D1;
          float nb = fmaf(vq.w, D2, vq.z*D3), db = D2*D3;
          float N = fmaf(nb, da, na*db);
          accS[0][s] = fmaf(N, frcp(da*db), accS[0][s]);
        }
        {
          float D0 = fmaf(es1.x, ea0, 1.f), D1 = fmaf(es1.y, ea1, 1.f);
          float D2 = fmaf(es1.z, ea2, 1.f), D3 = fmaf(es1.w, ea3, 1.f);
          float na = fmaf(vq.y, D0, vq.x*D1), da = D0*D1;
          float nb = fmaf(vq.w, D2, vq.z*D3), db = D2*D3;
          float N = fmaf(nb, da, na*db);
          accS[1][s] = fmaf(N, frcp(da*db), accS[1][s]);
        }
      }
    }
    // softmax over s (16 llo lanes share a t-row)
    #pragma unroll
    for (int i = 0; i < 2; i++) {
      float en[8];
      #pragma unroll
      for (int s = 0; s < 8; s++) en[s] = Vtot - 2.f*accS[i][s];
      float mx = en[0];
      #pragma unroll
      for (int s = 1; s < 8; s++) mx = fmaxf(mx, en[s]);
      for (int d = 1; d < 16; d <<= 1) mx = fmaxf(mx, __shfl_xor(mx, d));
      float sum = 0.f;
      #pragma unroll
      for (int s = 0; s < 8; s++) { float e = __expf(en[s] - mx); aw[half][i][s] = e; sum += e; }
      for (int d = 1; d < 16; d <<= 1) sum += __shfl_xor(sum, d);
      float dn = frcp(sum);
      #pragma unroll
      for (int s = 0; s < 8; s++) aw[half][i][s] *= dn;
    }
  }
  __syncthreads();
  // write softmax weights (aF over spE region) + stage eh f16 (over aeE region)
  float* aF = spE;                               // [128][130] f32
  u16* ehl = aeE;                                // [128][264] f16
  #pragma unroll
  for (int half = 0; half < 2; half++)
    #pragma unroll
    for (int i = 0; i < 2; i++)
      #pragma unroll
      for (int s = 0; s < 8; s++)
        aF[(half*64 + gid*2 + i)*130 + llo*8 + s] = aw[half][i][s];
  for (int c = tid; c < 4096; c += 512) {
    int s = c >> 5, ec = c & 31;
    const float* src = in.p[1] + ((size_t)(b*128 + s))*256 + ec*8;
    float4 f0 = *(const float4*)src, f1 = *(const float4*)(src+4);
    uint4 pk;
    pk.x = (u32)f2h(f0.x) | ((u32)f2h(f0.y) << 16);
    pk.y = (u32)f2h(f0.z) | ((u32)f2h(f0.w) << 16);
    pk.z = (u32)f2h(f1.x) | ((u32)f2h(f1.y) << 16);
    pk.w = (u32)f2h(f1.z) | ((u32)f2h(f1.w) << 16);
    *(uint4*)(ehl + s*264 + ec*8) = pk;
  }
  __syncthreads();
  // ctx + output partials: group owns 4 t rows; lane owns e = 8*llo (+128)
  int tj[4] = { gid*2, gid*2+1, 64+gid*2, 64+gid*2+1 };
  float cacc[4][16];
  #pragma unroll
  for (int j = 0; j < 4; j++)
    #pragma unroll
    for (int i = 0; i < 16; i++) cacc[j][i] = 0.f;
  #pragma unroll 1
  for (int s = 0; s < 128; s++) {
    float av[4];
    #pragma unroll
    for (int j = 0; j < 4; j++) av[j] = aF[tj[j]*130 + s];
    uint4 e0 = *(const uint4*)(ehl + s*264 + llo*8);
    uint4 e1 = *(const uint4*)(ehl + s*264 + 128 + llo*8);
    #pragma unroll
    for (int i = 0; i < 8; i++) {
      float f0 = upkh(e0, i), f1 = upkh(e1, i);
      #pragma unroll
      for (int j = 0; j < 4; j++) { cacc[j][i] += av[j]*f0; cacc[j][8+i] += av[j]*f1; }
    }
  }
  const int cb = 256 + g*512, ob = g*512;
  #pragma unroll
  for (int j = 0; j < 4; j++) {
    int t = tj[j];
    float pv = 0.f;
    #pragma unroll
    for (int i = 0; i < 8; i++) {
      pv += cacc[j][i]   * wout[cb + 8*llo + i];
      pv += cacc[j][8+i] * wout[cb + 128 + 8*llo + i];
    }
    uint4 o0 = *(const uint4*)(htop + ((size_t)(t+1)*NB + b)*NH + 8*llo);
    uint4 o1 = *(const uint4*)(htop + ((size_t)(t+1)*NB + b)*NH + 128 + 8*llo);
    #pragma unroll
    for (int i = 0; i < 8; i++) {
      pv += upk(o0, i) * wout[ob + 8*llo + i];
      pv += upk(o1, i) * wout[ob + 128 + 8*llo + i];
    }
    for (int d = 1; d < 16; d <<= 1) pv += __shfl_xor(pv, d);
    if (llo == 0) pw[t] = pv;
  }
}

__global__ void k_final(Ins in, char* ws, float* out) {
  int idx = blockIdx.x*256 + threadIdx.x;
  int b = idx >> 7, t = idx & 127;
  const float* pw = (const float*)(ws + WS_P);
  float p1 = pw[(size_t)b*NL + t];
  int t2 = (t >= 117) ? 127 : (t + 10);
  float p2 = pw[(size_t)NB*NL + (size_t)b*NL + t2];
  out[idx] = sigm(p1 + p2 + in.p[22][0]);
}

extern "C" void kernel_launch(void* const* d_in, const int* in_sizes, int n_in,
                              void* d_out, int out_size, void* d_ws, size_t ws_size,
                              hipStream_t stream) {
  Ins in;
  for (int i = 0; i < 23; i++) in.p[i] = (const float*)d_in[i];
  char* ws = (char*)d_ws;
  k_pack    <<<688, 256, 0, stream>>>(in, ws);
  k_hall0   <<<2048, 256, 0, stream>>>(in, ws);
  k_attn_enc<<<1024, 512, 0, stream>>>(in, ws);
  k_rec0    <<<dim3(64, 2), 512, 0, stream>>>(in, ws);
  if (ws_size >= WS_GI + 2*GI_SZ) {
    k_gi1    <<<1024, 512, 0, stream>>>(in, ws, 0, WS_GI);
    k_gi1    <<<1024, 512, 0, stream>>>(in, ws, 1, WS_GI + GI_SZ);
    k_rec1<1><<<dim3(64, 2), 512, 0, stream>>>(in, ws, 0, WS_GI, GI_SZ);
  } else if (ws_size >= WS_GI + GI_SZ) {
    k_gi1    <<<1024, 512, 0, stream>>>(in, ws, 0, WS_GI);
    k_rec1<1><<<dim3(64, 1), 512, 0, stream>>>(in, ws, 0, WS_GI, 0);
    k_gi1    <<<1024, 512, 0, stream>>>(in, ws, 1, WS_GI);
    k_rec1<1><<<dim3(64, 1), 512, 0, stream>>>(in, ws, 1, WS_GI, 0);
  } else {
    k_rec1<0><<<dim3(64, 2), 512, 0, stream>>>(in, ws, 0, 0, 0);
  }
  k_energy  <<<dim3(1024, 2), 512, 0, stream>>>(in, ws);
  k_final   <<<512, 256, 0, stream>>>(in, ws, (float*)d_out);
}